// Round 1
// baseline (383.679 us; speedup 1.0000x reference)
//
#include <hip/hip_runtime.h>

#define B_TOTAL 131072
#define NCOUNT 8
#define NL1 512
#define NL2 16
#define NL3 32
#define W_WIN 1024
#define BLK 128

__global__ __launch_bounds__(BLK) void nnue_fused_kernel(
    const float* __restrict__ accum,
    const float* __restrict__ us,
    const float* __restrict__ l1_w,
    const float* __restrict__ l1_b,
    const float* __restrict__ l2_w,
    const float* __restrict__ l2_b,
    const float* __restrict__ out_w,
    const float* __restrict__ out_b,
    const int*   __restrict__ psqt_indices,
    const int*   __restrict__ lsi,
    float*       __restrict__ out)
{
    __shared__ int list[W_WIN];
    __shared__ int cnt;
    const int l    = blockIdx.y;          // stack index owned by this block
    const int base = blockIdx.x * W_WIN;

    if (threadIdx.x == 0) cnt = 0;
    __syncthreads();

    // Phase 1: compact sample ids in this window matching our stack index.
    for (int i = threadIdx.x; i < W_WIN; i += BLK) {
        int s = base + i;
        if (lsi[s] == l) {
            int p = atomicAdd(&cnt, 1);
            list[p] = s;
        }
    }
    __syncthreads();
    const int n = cnt;

    // Wave-uniform weight base for this stack index (scalar-load friendly).
    const float4* __restrict__ w4 = (const float4*)l1_w + (size_t)l * NL2 * 256;

    for (int t = threadIdx.x; t < n; t += BLK) {
        const int s = list[t];
        const float* __restrict__ row  = accum + (size_t)s * 1040;
        const float4* __restrict__ row4 = (const float4*)row;

        float acc[NL2];
        #pragma unroll
        for (int j = 0; j < NL2; ++j) acc[j] = l1_b[l * NL2 + j];

        // L1 first half: w_main = row floats [0,512) ; weight cols [0,512)
        #pragma unroll 2
        for (int kc = 0; kc < 128; ++kc) {
            float4 a = row4[kc];
            #pragma unroll
            for (int j = 0; j < NL2; ++j) {
                float4 w = w4[j * 256 + kc];
                acc[j] += a.x * w.x + a.y * w.y + a.z * w.z + a.w * w.w;
            }
        }
        // L1 second half: b_main = row floats [520,1032) -> float4 idx 130..257 ;
        // weight cols [512,1024) -> chunk 128..255
        #pragma unroll 2
        for (int kc = 0; kc < 128; ++kc) {
            float4 a = row4[130 + kc];
            #pragma unroll
            for (int j = 0; j < NL2; ++j) {
                float4 w = w4[j * 256 + 128 + kc];
                acc[j] += a.x * w.x + a.y * w.y + a.z * w.z + a.w * w.w;
            }
        }

        // clip to [0,1]
        float l1y[NL2];
        #pragma unroll
        for (int j = 0; j < NL2; ++j)
            l1y[j] = fminf(fmaxf(acc[j], 0.0f), 1.0f);

        // L2 (32 x 16) + out (1 x 32), all wave-uniform weights
        const float* __restrict__ w2 = l2_w + (size_t)l * NL3 * NL2;
        float net = out_b[l];
        #pragma unroll 4
        for (int j = 0; j < NL3; ++j) {
            float s2 = l2_b[l * NL3 + j];
            #pragma unroll
            for (int k = 0; k < NL2; ++k) s2 += l1y[k] * w2[j * NL2 + k];
            float l2y = fminf(fmaxf(s2, 0.0f), 1.0f);
            net += l2y * out_w[l * NL3 + j];
        }

        // psqt term: w_psqt = row[512+pi], b_psqt = row[1032+pi]
        int pi = psqt_indices[s];
        float wp = row[NL1 + pi];
        float bp = row[2 * NL1 + NCOUNT + pi];
        out[s] = net + (wp - bp) * (us[s] - 0.5f);
    }
}

extern "C" void kernel_launch(void* const* d_in, const int* in_sizes, int n_in,
                              void* d_out, int out_size, void* d_ws, size_t ws_size,
                              hipStream_t stream) {
    const float* accum = (const float*)d_in[0];
    const float* us    = (const float*)d_in[1];
    const float* l1_w  = (const float*)d_in[2];
    const float* l1_b  = (const float*)d_in[3];
    const float* l2_w  = (const float*)d_in[4];
    const float* l2_b  = (const float*)d_in[5];
    const float* out_w = (const float*)d_in[6];
    const float* out_b = (const float*)d_in[7];
    const int*   psqt  = (const int*)d_in[8];
    const int*   lsi   = (const int*)d_in[9];
    float* out = (float*)d_out;

    dim3 grid(B_TOTAL / W_WIN, NCOUNT);
    nnue_fused_kernel<<<grid, BLK, 0, stream>>>(
        accum, us, l1_w, l1_b, l2_w, l2_b, out_w, out_b, psqt, lsi, out);
}